// Round 7
// baseline (72.285 us; speedup 1.0000x reference)
//
#include <hip/hip_runtime.h>
#include <stdint.h>

// ---------------------------------------------------------------------------
// FractalLinear: IFS chaos game (JAX threefry-exact) + bilinear gather/scatter
// Round 7 structure:
//   K1 chaos (8 lanes/point)        -> rec[1000] = {x_low, x_w, y_low, y_w}
//   K2 build (1 block)              -> CSR over y-bins (scatter->gather
//        inversion; rec is row-independent!), heavy-bin list, x-sorted order
//   K3 apply (1 row/block, 256 thr) -> gather XV (x-sorted), CSR-accumulate,
//        coalesced nontemporal stores. No atomics, 4.4 KB LDS, 8 blk/CU.
// ---------------------------------------------------------------------------
#ifndef PRNG_PARTITIONABLE
#define PRNG_PARTITIONABLE 1
#endif

namespace {

constexpr int kH  = 8192;
constexpr int kW  = 16384;
constexpr int kNT = 8;
constexpr int kNP = 1000;
constexpr int kCI = 10;
constexpr int kHeavy = 128;          // bin count >= this -> wave-reduced
constexpr int kMaxHeavy = 32;        // 2000/128 = 15.6 -> <=15, cap 32

// ws layout (byte offsets, 16B-aligned)
constexpr size_t kOffRec    = 0;        // 1000 * int4   = 16000 -> 16384
constexpr size_t kOffRowPtr = 16384;    // 8193 * u32    = 32772 -> 33024
constexpr size_t kOffEnt    = 49408;    // 2000 * uint2  = 16000 -> 16128
constexpr size_t kOffOrder  = 65536;    // 1000 * u32    =  4000
constexpr size_t kOffHeavy  = 69632;    // 32 * u32 + u32 count

typedef float floatx4 __attribute__((ext_vector_type(4)));  // nontemporal-OK

__device__ __forceinline__ uint32_t rotl32(uint32_t x, int n) {
  return (x << n) | (x >> (32 - n));
}

// Threefry-2x32, 20 rounds (Random123 / JAX convention).
__device__ void threefry2x32(uint32_t k0, uint32_t k1, uint32_t c0, uint32_t c1,
                             uint32_t& o0, uint32_t& o1) {
  const uint32_t ks2 = k0 ^ k1 ^ 0x1BD11BDAu;
  uint32_t x0 = c0 + k0, x1 = c1 + k1;
#define TF_R(r) { x0 += x1; x1 = rotl32(x1, (r)); x1 ^= x0; }
  TF_R(13) TF_R(15) TF_R(26) TF_R(6)
  x0 += k1;  x1 += ks2 + 1u;
  TF_R(17) TF_R(29) TF_R(16) TF_R(24)
  x0 += ks2; x1 += k0 + 2u;
  TF_R(13) TF_R(15) TF_R(26) TF_R(6)
  x0 += k0;  x1 += k1 + 3u;
  TF_R(17) TF_R(29) TF_R(16) TF_R(24)
  x0 += k1;  x1 += ks2 + 4u;
  TF_R(13) TF_R(15) TF_R(26) TF_R(6)
  x0 += ks2; x1 += k0 + 5u;
#undef TF_R
  o0 = x0; o1 = x1;
}

__device__ __forceinline__ uint32_t random_bits32(uint32_t k0, uint32_t k1,
                                                  uint32_t i, uint32_t size) {
#if PRNG_PARTITIONABLE
  uint32_t o0, o1;
  threefry2x32(k0, k1, 0u /* hi(i) */, i, o0, o1);
  (void)size;
  return o0 ^ o1;
#else
  const uint32_t half = size / 2u;
  const uint32_t j = (i < half) ? i : (i - half);
  uint32_t o0, o1;
  threefry2x32(k0, k1, j, j + half, o0, o1);
  return (i < half) ? o0 : o1;
#endif
}

__device__ __forceinline__ float u01(uint32_t bits) {
  return __uint_as_float((bits >> 9) | 0x3f800000u) - 1.0f;
}

// x86 cvttss2si semantics: out-of-range / NaN -> INT_MIN (matches CPU-ref).
__device__ __forceinline__ int cvt_f32_i32_x86(float v) {
  if (!(v >= -2147483648.0f && v < 2147483648.0f)) return (int)0x80000000;
  return (int)v;
}

// ---------------------------------------------------------------------------
// Kernel 1: chaos game, 8 lanes per point (one transform each).
// ---------------------------------------------------------------------------
__global__ __launch_bounds__(256) void fractal_chaos(
    const float* __restrict__ dna, int4* __restrict__ rec) {
  const int gid  = blockIdx.x * blockDim.x + threadIdx.x;
  const int n    = gid >> 3;
  const int lane = gid & 7;
  if (n >= kNP) return;

  uint32_t kp0, kp1, kg0, kg1;
#if PRNG_PARTITIONABLE
  threefry2x32(0u, 1u, 0u, 0u, kp0, kp1);
  threefry2x32(0u, 1u, 0u, 1u, kg0, kg1);
#else
  uint32_t a0, a1, b0, b1;
  threefry2x32(0u, 1u, 0u, 2u, a0, a1);
  threefry2x32(0u, 1u, 1u, 3u, b0, b1);
  kp0 = a0; kp1 = b0; kg0 = a1; kg1 = b1;
#endif

  const float A  = dna[lane * 7 + 0], Bb = dna[lane * 7 + 1];
  const float C  = dna[lane * 7 + 2], D  = dna[lane * 7 + 3];
  const float E  = dna[lane * 7 + 4], F  = dna[lane * 7 + 5];
  const float P  = dna[lane * 7 + 6];

  float z[kCI];
  #pragma unroll
  for (int i = 0; i < kCI; ++i) {
    uint32_t ki0, ki1;
    threefry2x32(kg0, kg1, 0u, (uint32_t)i, ki0, ki1);
    const uint32_t bb = random_bits32(ki0, ki1, (uint32_t)(n * kNT + lane),
                                      (uint32_t)(kNP * kNT));
    const float u = fmaxf(u01(bb), 1.17549435e-38f);
    const float g = -logf(-logf(u));
    z[i] = P + g;
  }

  const uint32_t bx = random_bits32(kp0, kp1, (uint32_t)(2 * n),     2u * kNP);
  const uint32_t by = random_bits32(kp0, kp1, (uint32_t)(2 * n + 1), 2u * kNP);
  float px = u01(bx) * 2.0f - 1.0f;
  float py = u01(by) * 2.0f - 1.0f;

  #pragma unroll
  for (int i = 0; i < kCI; ++i) {
    float zb = z[i];
    int   bt = lane;
    #pragma unroll
    for (int m = 1; m < 8; m <<= 1) {
      const float zo = __shfl_xor(zb, m, 8);
      const int   to = __shfl_xor(bt, m, 8);
      if (zo > zb || (zo == zb && to < bt)) { zb = zo; bt = to; }
    }
    const float A_ = __shfl(A,  bt, 8), B_ = __shfl(Bb, bt, 8);
    const float C_ = __shfl(C,  bt, 8), D_ = __shfl(D,  bt, 8);
    const float E_ = __shfl(E,  bt, 8), F_ = __shfl(F,  bt, 8);
    const float nx = A_ * px + B_ * py + E_;
    const float ny = C_ * px + D_ * py + F_;
    px = nx; py = ny;
  }

  if (lane == 0) {
    const float xc = ((px + 1.0f) * 0.5f) * (float)(kW - 1);
    const float yc = ((py + 1.0f) * 0.5f) * (float)(kH - 1);
    int xl = cvt_f32_i32_x86(floorf(xc));
    int yl = cvt_f32_i32_x86(floorf(yc));
    xl = min(max(xl, 0), kW - 2);
    yl = min(max(yl, 0), kH - 2);
    const float xw = xc - (float)xl;   // NOT clipped (matches reference)
    const float yw = yc - (float)yl;
    rec[n] = make_int4(xl, __float_as_int(xw), yl, __float_as_int(yw));
  }
}

// ---------------------------------------------------------------------------
// Kernel 2 (single block, 1024 thr): build CSR over y-bins + heavy list +
// x-sorted point order. Work: two counting sorts + one 8192 scan. ~few us.
// ---------------------------------------------------------------------------
__global__ __launch_bounds__(1024) void fractal_build(
    const int4* __restrict__ rec, uint32_t* __restrict__ rowptr,
    uint2* __restrict__ ent, uint32_t* __restrict__ order,
    uint32_t* __restrict__ heavy /* [0]=count, [1..32]=bins */) {
  __shared__ uint32_t cnt[kH];          // 32 KB: counts -> offsets -> cursors
  __shared__ uint32_t seg[1024];
  __shared__ uint32_t heavyL[kMaxHeavy];
  __shared__ uint32_t nHeavyL;

  const int t = threadIdx.x;
  if (t == 0) nHeavyL = 0;

  // --- phase A: y-bin counts ---
  #pragma unroll
  for (int i = 0; i < kH / 1024; ++i) cnt[t + i * 1024] = 0;
  __syncthreads();

  int yl = 0, xl = 0;
  float w0 = 0.f, w1 = 0.f;
  const bool hav = t < kNP;
  if (hav) {
    const int4 r = rec[t];
    xl = r.x;
    yl = r.z;
    const float yw = __int_as_float(r.w);
    w0 = (1.0f - yw) * (1.0f / (float)kNP);   // fold 1/NUM_POINTS into weight
    w1 = yw * (1.0f / (float)kNP);
    atomicAdd(&cnt[yl], 1u);
    atomicAdd(&cnt[yl + 1], 1u);
  }
  __syncthreads();

  // --- phase B: exclusive scan of cnt[8192] ---
  uint32_t s = 0;
  #pragma unroll
  for (int i = 0; i < 8; ++i) s += cnt[t * 8 + i];
  seg[t] = s;
  __syncthreads();
  #pragma unroll
  for (int o = 1; o < 1024; o <<= 1) {
    uint32_t v = (t >= o) ? seg[t - o] : 0u;
    __syncthreads();
    seg[t] += v;
    __syncthreads();
  }
  uint32_t run = (t > 0) ? seg[t - 1] : 0u;
  const uint32_t total = seg[1023];
  #pragma unroll
  for (int i = 0; i < 8; ++i) {
    const int h = t * 8 + i;
    const uint32_t c = cnt[h];
    if (c >= (uint32_t)kHeavy) {                 // heavy-bin detection
      const uint32_t p = atomicAdd(&nHeavyL, 1u);
      if (p < kMaxHeavy) heavyL[p] = (uint32_t)h;
    }
    cnt[h] = run;                                 // exclusive offset
    rowptr[h] = run;
    run += c;
  }
  if (t == 1023) rowptr[kH] = total;              // == 2000
  __syncthreads();

  // --- phase C: scatter entries (cursor = cnt) ---
  if (hav) {
    const uint32_t e0 = atomicAdd(&cnt[yl], 1u);
    ent[e0] = make_uint2((uint32_t)t, __float_as_uint(w0));
    const uint32_t e1 = atomicAdd(&cnt[yl + 1], 1u);
    ent[e1] = make_uint2((uint32_t)t, __float_as_uint(w1));
  }
  // heavy list to global
  if (t == 0) heavy[0] = min(nHeavyL, (uint32_t)kMaxHeavy);
  if (t < kMaxHeavy && t < nHeavyL) heavy[1 + t] = heavyL[t];
  __syncthreads();

  // --- phase D: x-sorted order (counting sort over 1024 buckets of 16 cols)
  if (t < 1024) cnt[t] = 0;
  __syncthreads();
  const int bx = xl >> 4;
  if (hav) atomicAdd(&cnt[bx], 1u);
  __syncthreads();
  seg[t] = cnt[t];
  __syncthreads();
  #pragma unroll
  for (int o = 1; o < 1024; o <<= 1) {
    uint32_t v = (t >= o) ? seg[t - o] : 0u;
    __syncthreads();
    seg[t] += v;
    __syncthreads();
  }
  cnt[t] = (t > 0) ? seg[t - 1] : 0u;
  __syncthreads();
  if (hav) {
    const uint32_t p = atomicAdd(&cnt[bx], 1u);
    order[p] = (uint32_t)t;
  }
}

// ---------------------------------------------------------------------------
// Kernel 3: one row/block, 256 threads, 4.4 KB LDS (8 blk/CU, 32 waves/CU).
//  ph1: gather 1000 x-values in x-sorted order -> LDS
//  ph2: wave-parallel reduce of heavy bins (clipped-edge hotspots)
//  ph3: thread-per-4-bins CSR accumulate + coalesced nontemporal store
// ---------------------------------------------------------------------------
__global__ __launch_bounds__(256) void fractal_apply(
    const float* __restrict__ x, const float* __restrict__ bias,
    const int4* __restrict__ rec, const uint32_t* __restrict__ rowptr,
    const uint2* __restrict__ ent, const uint32_t* __restrict__ order,
    const uint32_t* __restrict__ heavy, float* __restrict__ out) {
  __shared__ float XV[kNP];
  __shared__ uint32_t heavyH[kMaxHeavy];
  __shared__ float heavyS[kMaxHeavy];
  __shared__ uint32_t nH;

  const int tid = threadIdx.x;
  const int b   = blockIdx.x;
  const float* __restrict__ xrow = x + (size_t)b * kW;

  if (tid == 0) nH = heavy[0];
  if (tid < kMaxHeavy) heavyH[tid] = heavy[1 + tid];

  // --- ph1: gather (x-sorted order -> ascending lines within each wave) ---
  #pragma unroll
  for (int j = 0; j < 4; ++j) {
    const int i = tid + j * 256;
    if (i < kNP) {
      const uint32_t n = order[i];
      const int4 r = rec[n];
      const int   xl = r.x;
      const float xw = __int_as_float(r.y);
      XV[n] = xrow[xl] * (1.0f - xw) + xrow[xl + 1] * xw;
    }
  }
  __syncthreads();

  // --- ph2: heavy bins, one wave per bin (no block barriers inside) ---
  {
    const int wid  = tid >> 6;
    const int lane = tid & 63;
    const uint32_t nh = nH;
    for (uint32_t k = wid; k < nh; k += 4) {
      const uint32_t h = heavyH[k];
      const uint32_t s = rowptr[h], e = rowptr[h + 1];
      float p = 0.f;
      for (uint32_t i = s + lane; i < e; i += 64) {
        const uint2 en = ent[i];
        p += XV[en.x] * __uint_as_float(en.y);
      }
      #pragma unroll
      for (int o = 32; o > 0; o >>= 1) p += __shfl_down(p, o);
      if (lane == 0) heavyS[k] = p;
    }
  }
  __syncthreads();

  // --- ph3: per-bin accumulate, coalesced output ---
  const uint32_t nh = nH;
  const int4* __restrict__ rp4 = reinterpret_cast<const int4*>(rowptr);
  const floatx4* __restrict__ bias4 = reinterpret_cast<const floatx4*>(bias);
  floatx4* __restrict__ out4 = reinterpret_cast<floatx4*>(out + (size_t)b * kH);

  #pragma unroll
  for (int j = 0; j < 8; ++j) {
    const int g = j * 256 + tid;               // float4 group in [0, 2048)
    const int4 rpv = rp4[g];                   // rowptr[4g .. 4g+3]
    const uint32_t rp_end = rowptr[4 * g + 4];
    uint32_t rps[5] = {(uint32_t)rpv.x, (uint32_t)rpv.y, (uint32_t)rpv.z,
                       (uint32_t)rpv.w, rp_end};
    floatx4 v;
    #pragma unroll
    for (int c = 0; c < 4; ++c) {
      const uint32_t s = rps[c], e = rps[c + 1];
      float val = 0.f;
      if (e - s >= (uint32_t)kHeavy) {
        const uint32_t h = (uint32_t)(4 * g + c);
        for (uint32_t k = 0; k < nh; ++k)
          if (heavyH[k] == h) { val = heavyS[k]; break; }
      } else {
        for (uint32_t i = s; i < e; ++i) {
          const uint2 en = ent[i];
          val += XV[en.x] * __uint_as_float(en.y);
        }
      }
      v[c] = val;
    }
    v += bias4[g];
    __builtin_nontemporal_store(v, &out4[g]);
  }
}

}  // namespace

extern "C" void kernel_launch(void* const* d_in, const int* in_sizes, int n_in,
                              void* d_out, int out_size, void* d_ws, size_t ws_size,
                              hipStream_t stream) {
  const float* x    = (const float*)d_in[0];   // (2048, 16384)
  const float* dna  = (const float*)d_in[1];   // (56,)
  const float* bias = (const float*)d_in[2];   // (8192,)
  float* out = (float*)d_out;                  // (2048, 8192)

  char* ws = (char*)d_ws;
  int4*     rec    = (int4*)(ws + kOffRec);
  uint32_t* rowptr = (uint32_t*)(ws + kOffRowPtr);
  uint2*    ent    = (uint2*)(ws + kOffEnt);
  uint32_t* order  = (uint32_t*)(ws + kOffOrder);
  uint32_t* heavy  = (uint32_t*)(ws + kOffHeavy);

  fractal_chaos<<<(kNP * 8 + 255) / 256, 256, 0, stream>>>(dna, rec);
  fractal_build<<<1, 1024, 0, stream>>>(rec, rowptr, ent, order, heavy);

  const int B = in_sizes[0] / kW;              // 2048
  fractal_apply<<<B, 256, 0, stream>>>(x, bias, rec, rowptr, ent, order,
                                       heavy, out);
}

// Round 8
// 48.393 us; speedup vs baseline: 1.4937x; 1.4937x over previous
//
#include <hip/hip_runtime.h>
#include <stdint.h>

// ---------------------------------------------------------------------------
// FractalLinear: IFS chaos game (JAX threefry-exact) + bilinear gather/scatter
// Round 8 = round-4 structure (best so far, 46.5us) + hot-bin register
// privatization: escaped points clip to yl in {0, 8190}, so those 4 bins
// take hundreds of same-address LDS atomics (serialized). Divert them to
// per-thread registers + wave reduce + 1 atomic/wave/bin.
// ---------------------------------------------------------------------------
#ifndef PRNG_PARTITIONABLE
#define PRNG_PARTITIONABLE 1
#endif

namespace {

constexpr int kH  = 8192;
constexpr int kW  = 16384;
constexpr int kNT = 8;
constexpr int kNP = 1000;
constexpr int kCI = 10;
constexpr int kRPB = 2;          // batch rows per apply-block

typedef float floatx4 __attribute__((ext_vector_type(4)));  // nontemporal-OK

__device__ __forceinline__ uint32_t rotl32(uint32_t x, int n) {
  return (x << n) | (x >> (32 - n));
}

// Threefry-2x32, 20 rounds (Random123 / JAX convention).
__device__ void threefry2x32(uint32_t k0, uint32_t k1, uint32_t c0, uint32_t c1,
                             uint32_t& o0, uint32_t& o1) {
  const uint32_t ks2 = k0 ^ k1 ^ 0x1BD11BDAu;
  uint32_t x0 = c0 + k0, x1 = c1 + k1;
#define TF_R(r) { x0 += x1; x1 = rotl32(x1, (r)); x1 ^= x0; }
  TF_R(13) TF_R(15) TF_R(26) TF_R(6)
  x0 += k1;  x1 += ks2 + 1u;
  TF_R(17) TF_R(29) TF_R(16) TF_R(24)
  x0 += ks2; x1 += k0 + 2u;
  TF_R(13) TF_R(15) TF_R(26) TF_R(6)
  x0 += k0;  x1 += k1 + 3u;
  TF_R(17) TF_R(29) TF_R(16) TF_R(24)
  x0 += k1;  x1 += ks2 + 4u;
  TF_R(13) TF_R(15) TF_R(26) TF_R(6)
  x0 += ks2; x1 += k0 + 5u;
#undef TF_R
  o0 = x0; o1 = x1;
}

__device__ __forceinline__ uint32_t random_bits32(uint32_t k0, uint32_t k1,
                                                  uint32_t i, uint32_t size) {
#if PRNG_PARTITIONABLE
  uint32_t o0, o1;
  threefry2x32(k0, k1, 0u /* hi(i) */, i, o0, o1);
  (void)size;
  return o0 ^ o1;
#else
  const uint32_t half = size / 2u;
  const uint32_t j = (i < half) ? i : (i - half);
  uint32_t o0, o1;
  threefry2x32(k0, k1, j, j + half, o0, o1);
  return (i < half) ? o0 : o1;
#endif
}

__device__ __forceinline__ float u01(uint32_t bits) {
  return __uint_as_float((bits >> 9) | 0x3f800000u) - 1.0f;
}

// x86 cvttss2si semantics: out-of-range / NaN -> INT_MIN (matches CPU-ref).
__device__ __forceinline__ int cvt_f32_i32_x86(float v) {
  if (!(v >= -2147483648.0f && v < 2147483648.0f)) return (int)0x80000000;
  return (int)v;
}

// ---------------------------------------------------------------------------
// Kernel 1: chaos game, 8 lanes per point (one transform each).
// Gumbel logits are trajectory-independent -> precomputed with full ILP;
// the serial part is only 10x (8-lane argmax-reduce + affine).
// ---------------------------------------------------------------------------
__global__ __launch_bounds__(256) void fractal_chaos(
    const float* __restrict__ dna, int4* __restrict__ rec) {
  const int gid  = blockIdx.x * blockDim.x + threadIdx.x;
  const int n    = gid >> 3;        // point index
  const int lane = gid & 7;         // transform index owned by this lane
  if (n >= kNP) return;             // whole 8-lane group exits together

  // base key = jax.random.key(1) -> (0, 1); kp, kg = split(key, 2)
  uint32_t kp0, kp1, kg0, kg1;
#if PRNG_PARTITIONABLE
  threefry2x32(0u, 1u, 0u, 0u, kp0, kp1);
  threefry2x32(0u, 1u, 0u, 1u, kg0, kg1);
#else
  uint32_t a0, a1, b0, b1;
  threefry2x32(0u, 1u, 0u, 2u, a0, a1);
  threefry2x32(0u, 1u, 1u, 3u, b0, b1);
  kp0 = a0; kp1 = b0; kg0 = a1; kg1 = b1;
#endif

  // this lane's transform parameters (shuffled to the group after argmax)
  const float A  = dna[lane * 7 + 0], Bb = dna[lane * 7 + 1];
  const float C  = dna[lane * 7 + 2], D  = dna[lane * 7 + 3];
  const float E  = dna[lane * 7 + 4], F  = dna[lane * 7 + 5];
  const float P  = dna[lane * 7 + 6];

  // precompute z[i] = logits + gumbel for all iterations (point-independent)
  float z[kCI];
  #pragma unroll
  for (int i = 0; i < kCI; ++i) {
    uint32_t ki0, ki1;
    threefry2x32(kg0, kg1, 0u, (uint32_t)i, ki0, ki1);   // fold_in(kg, i)
    const uint32_t bb = random_bits32(ki0, ki1, (uint32_t)(n * kNT + lane),
                                      (uint32_t)(kNP * kNT));
    const float u = fmaxf(u01(bb), 1.17549435e-38f);
    const float g = -logf(-logf(u));
    z[i] = P + g;
  }

  // initial point: uniform(kp, (1000,2)) * 2 - 1 (computed redundantly per lane)
  const uint32_t bx = random_bits32(kp0, kp1, (uint32_t)(2 * n),     2u * kNP);
  const uint32_t by = random_bits32(kp0, kp1, (uint32_t)(2 * n + 1), 2u * kNP);
  float px = u01(bx) * 2.0f - 1.0f;
  float py = u01(by) * 2.0f - 1.0f;

  #pragma unroll
  for (int i = 0; i < kCI; ++i) {
    // argmax over the 8 lanes, first-index tiebreak (matches jnp.argmax)
    float zb = z[i];
    int   bt = lane;
    #pragma unroll
    for (int m = 1; m < 8; m <<= 1) {
      const float zo = __shfl_xor(zb, m, 8);
      const int   to = __shfl_xor(bt, m, 8);
      if (zo > zb || (zo == zb && to < bt)) { zb = zo; bt = to; }
    }
    const float A_ = __shfl(A,  bt, 8), B_ = __shfl(Bb, bt, 8);
    const float C_ = __shfl(C,  bt, 8), D_ = __shfl(D,  bt, 8);
    const float E_ = __shfl(E,  bt, 8), F_ = __shfl(F,  bt, 8);
    const float nx = A_ * px + B_ * py + E_;
    const float ny = C_ * px + D_ * py + F_;
    px = nx; py = ny;
  }

  if (lane == 0) {
    const float xc = ((px + 1.0f) * 0.5f) * (float)(kW - 1);
    const float yc = ((py + 1.0f) * 0.5f) * (float)(kH - 1);
    int xl = cvt_f32_i32_x86(floorf(xc));
    int yl = cvt_f32_i32_x86(floorf(yc));
    xl = min(max(xl, 0), kW - 2);
    yl = min(max(yl, 0), kH - 2);
    const float xw = xc - (float)xl;   // NOT clipped (matches reference)
    const float yw = yc - (float)yl;
    rec[n] = make_int4(xl, __float_as_int(xw), yl, __float_as_int(yw));
  }
}

// ---------------------------------------------------------------------------
// Kernel 2: 2 batch rows per block, 1024 threads (round-4 structure).
// Interior bins: plain LDS atomicAdd (avg 0.24 entries/bin -> low contention).
// Clip-edge bins {0,1,kH-2,kH-1}: register accumulate + 64-lane shfl reduce +
// one atomic per wave per bin (kills the serialized same-address hotspot).
// ---------------------------------------------------------------------------
__global__ __launch_bounds__(1024) void fractal_apply(
    const float* __restrict__ x, const float* __restrict__ bias,
    const int4* __restrict__ rec, float* __restrict__ out, int B) {
  __shared__ __align__(16) float acc[kRPB * kH];
  const int b0 = blockIdx.x * kRPB;
  const int nrows = min(kRPB, B - b0);
  const int tid = threadIdx.x;

  float4* acc4 = reinterpret_cast<float4*>(acc);
  constexpr int N4 = kRPB * kH / 4;            // 4096
  for (int i = tid; i < N4; i += 1024)
    acc4[i] = make_float4(0.f, 0.f, 0.f, 0.f);
  __syncthreads();

  // per-thread point record (threads 0..999)
  const bool havept = tid < kNP;
  int xl = 0, yl = 0;
  float xw = 0.f, yw = 0.f, xw0 = 0.f, w0 = 0.f;
  if (havept) {
    const int4 r = rec[tid];
    xl = r.x; xw = __int_as_float(r.y);
    yl = r.z; yw = __int_as_float(r.w);
    xw0 = 1.0f - xw; w0 = 1.0f - yw;
  }
  const bool hotLo = havept && (yl == 0);
  const bool hotHi = havept && (yl == kH - 2);
  const bool interior = havept && !hotLo && !hotHi;

  const float* xp = x + (size_t)b0 * kW + xl;
  #pragma unroll
  for (int rI = 0; rI < kRPB; ++rI) {
    if (rI >= nrows) break;
    float c0 = 0.f, c1 = 0.f;
    if (havept) {
      const float xv = xp[(size_t)rI * kW] * xw0 + xp[(size_t)rI * kW + 1] * xw;
      c0 = xv * w0;
      c1 = xv * yw;
    }
    if (interior) {
      atomicAdd(&acc[rI * kH + yl],     c0);
      atomicAdd(&acc[rI * kH + yl + 1], c1);
    }
    // hot bins: register -> wave reduce -> one atomic per wave per bin
    float e0 = hotLo ? c0 : 0.f;
    float e1 = hotLo ? c1 : 0.f;
    float e2 = hotHi ? c0 : 0.f;
    float e3 = hotHi ? c1 : 0.f;
    #pragma unroll
    for (int o = 32; o > 0; o >>= 1) {
      e0 += __shfl_xor(e0, o);
      e1 += __shfl_xor(e1, o);
      e2 += __shfl_xor(e2, o);
      e3 += __shfl_xor(e3, o);
    }
    if ((tid & 63) == 0) {
      if (e0 != 0.f) atomicAdd(&acc[rI * kH + 0],      e0);
      if (e1 != 0.f) atomicAdd(&acc[rI * kH + 1],      e1);
      if (e2 != 0.f) atomicAdd(&acc[rI * kH + kH - 2], e2);
      if (e3 != 0.f) atomicAdd(&acc[rI * kH + kH - 1], e3);
    }
  }
  __syncthreads();

  // epilogue: out = acc/1000 + bias (nontemporal: write-once, never re-read)
  const floatx4* __restrict__ bias4 = reinterpret_cast<const floatx4*>(bias);
  for (int i = tid; i < N4; i += 1024) {
    const int row = i >> 11;          // i / (kH/4)
    const int col = i & 2047;         // i % (kH/4)
    if (row < nrows) {
      const float4 a  = acc4[i];
      const floatx4 bi = bias4[col];
      floatx4 o;
      o.x = a.x / 1000.0f + bi.x;
      o.y = a.y / 1000.0f + bi.y;
      o.z = a.z / 1000.0f + bi.z;
      o.w = a.w / 1000.0f + bi.w;
      floatx4* dst = reinterpret_cast<floatx4*>(out + (size_t)(b0 + row) * kH);
      __builtin_nontemporal_store(o, &dst[col]);
    }
  }
}

}  // namespace

extern "C" void kernel_launch(void* const* d_in, const int* in_sizes, int n_in,
                              void* d_out, int out_size, void* d_ws, size_t ws_size,
                              hipStream_t stream) {
  const float* x    = (const float*)d_in[0];   // (2048, 16384)
  const float* dna  = (const float*)d_in[1];   // (56,)
  const float* bias = (const float*)d_in[2];   // (8192,)
  float* out = (float*)d_out;                  // (2048, 8192)
  int4* rec = (int4*)d_ws;                     // 1000 * 16B scratch

  fractal_chaos<<<(kNP * 8 + 255) / 256, 256, 0, stream>>>(dna, rec);

  const int B = in_sizes[0] / kW;              // 2048
  fractal_apply<<<(B + kRPB - 1) / kRPB, 1024, 0, stream>>>(x, bias, rec, out, B);
}